// Round 6
// baseline (277.791 us; speedup 1.0000x reference)
//
#include <hip/hip_runtime.h>
#include <hip/hip_fp16.h>
#include <math.h>

// Problem constants: NE=1e6, NR=1000, D=32, B=2^20, CURV=1
#define NR_ 1000
#define NE_ 1000000
#define D_ 32
#define HALF_ 16
#define EMB_DIM 33            // fp32 entity row: [x0, spatial(32)]
#define TAB_STRIDE 80         // 320 B/row: FIVE 64B-aligned blocks (was 272B)
#define H16_BYTES ((size_t)NE_ * 64)   // fp16 table: 16 uints/row, 64 B rows
#define ROWS_PER_BLOCK 64
#define FLOATS_PER_BLOCK (ROWS_PER_BLOCK * EMB_DIM)   // 2112
#define REPACK_BLOCKS (NE_ / ROWS_PER_BLOCK)          // 15625
#define TAB_BLOCKS 16         // 16*256 = 4096 >= NR*4 lanes

// ---------------------------------------------------------------------------
// Kernel 0 (fused prep), LDS-staged streaming (R5-proven, ~40 us).
// Blocks [0, REPACK_BLOCKS): 64 rows/block staged via coalesced dword streams
// into LDS, then packed fp16 INTERLEAVED (chunk q = {sp[4q..4q+3],
// sp[16+4q..+3]}) and written as one uint4/thread (4 KB contiguous/block).
// Blocks [REPACK_BLOCKS, +TAB_BLOCKS): relation table, NEW 64B-ALIGNED layout
// (stride 80 floats = 320 B, rows 64B-aligned):
//   bytes [  0, 64): cos(rot)[0:16)
//   bytes [ 64,128): sin(rot)[0:16)
//   bytes [128,192): kt dims interleaved a-half ([32+4q..36+4q) = dims 4q..)
//   bytes [192,256): kt b-half ([48+4q..52+4q) = dims 16+4q..)
//   bytes [256,272): {cosh(rap0), sinh(rap0), cosh(vn), pad}; rest pad.
// Every per-group 64 B tab access in the main kernel is now exactly ONE
// cache-line request (the old 272 B stride split ~25% of them).
// ---------------------------------------------------------------------------
__global__ __launch_bounds__(256) void prep_kernel(
    const float* __restrict__ emb, const float* __restrict__ boost_w,
    const float* __restrict__ rot_w, const float* __restrict__ trans_w,
    unsigned int* __restrict__ h16, float* __restrict__ tab) {
  const int b = blockIdx.x;
  if (b < REPACK_BLOCKS) {
    __shared__ float s[FLOATS_PER_BLOCK];
    const int tid = threadIdx.x;
    const float* __restrict__ src = emb + (size_t)b * FLOATS_PER_BLOCK;
    #pragma unroll
    for (int k = 0; k < 8; ++k) s[tid + k * 256] = src[tid + k * 256];
    if (tid < FLOATS_PER_BLOCK - 2048) s[2048 + tid] = src[2048 + tid];
    __syncthreads();

    const int r = tid >> 2, q = tid & 3;                 // row 0..63, chunk
    const float* p = s + r * EMB_DIM + 1 + 4 * q;        // a-dims 4q..4q+3
    float a0 = p[0], a1 = p[1], a2 = p[2], a3 = p[3];
    float b0 = p[HALF_], b1 = p[HALF_ + 1], b2 = p[HALF_ + 2], b3 = p[HALF_ + 3];
    union { __half2 h; unsigned int u; } c0, c1, c2, c3;
    c0.h = __half2(__float2half_rn(a0), __float2half_rn(a1));
    c1.h = __half2(__float2half_rn(a2), __float2half_rn(a3));
    c2.h = __half2(__float2half_rn(b0), __float2half_rn(b1));
    c3.h = __half2(__float2half_rn(b2), __float2half_rn(b3));
    uint4 v = make_uint4(c0.u, c1.u, c2.u, c3.u);
    const size_t row = (size_t)b * ROWS_PER_BLOCK + r;
    *reinterpret_cast<uint4*>(h16 + row * 16 + 4 * q) = v;   // 16B aligned
    return;
  }
  // ---- tab build: 4 lanes per relation ----
  const int t = (b - REPACK_BLOCKS) * 256 + threadIdx.x;
  const int r = t >> 2, q = t & 3;
  if (r >= NR_) return;
  const float* ro = rot_w   + (size_t)r * D_ + 4 * q;       // rot dims 4q..
  const float* ta = trans_w + (size_t)r * D_ + 4 * q;       // trans a-dims
  const float* tb = ta + HALF_;                             // trans b-dims
  float* o = tab + (size_t)r * TAB_STRIDE;

  float ta0 = ta[0], ta1 = ta[1], ta2 = ta[2], ta3 = ta[3];
  float tb0 = tb[0], tb1 = tb[1], tb2 = tb[2], tb3 = tb[3];
  float s2 = ta0 * ta0;
  s2 = fmaf(ta1, ta1, s2); s2 = fmaf(ta2, ta2, s2); s2 = fmaf(ta3, ta3, s2);
  s2 = fmaf(tb0, tb0, s2); s2 = fmaf(tb1, tb1, s2);
  s2 = fmaf(tb2, tb2, s2); s2 = fmaf(tb3, tb3, s2);
  s2 += __shfl_xor(s2, 1);
  s2 += __shfl_xor(s2, 2);

  float vn = sqrtf(fmaxf(0.01f * s2, 1e-6f));
  float k  = sinhf(vn) / vn * 0.1f;

  #pragma unroll
  for (int m = 0; m < 4; ++m) {
    float th = ro[m];
    o[4 * q + m]         = cosf(th);   // cos dims 4q+m
    o[HALF_ + 4 * q + m] = sinf(th);   // sin dims 4q+m
  }
  o[32 + 4 * q + 0] = k * ta0; o[32 + 4 * q + 1] = k * ta1;
  o[32 + 4 * q + 2] = k * ta2; o[32 + 4 * q + 3] = k * ta3;
  o[48 + 4 * q + 0] = k * tb0; o[48 + 4 * q + 1] = k * tb1;
  o[48 + 4 * q + 2] = k * tb2; o[48 + 4 * q + 3] = k * tb3;

  if (q == 0) {
    float rap = fminf(fmaxf(boost_w[(size_t)r * D_], -2.f), 2.f);
    o[64] = coshf(rap);
    o[65] = sinhf(rap);
    o[66] = coshf(vn);
    o[67] = 0.f;
  }
}

// ---------------------------------------------------------------------------
// Per-element score (identical arithmetic to the R5-proven path).
// All 4 lanes of the group return the full reduced value (shfl_xor butterfly).
// ---------------------------------------------------------------------------
__device__ __forceinline__ float score_one(
    const int q, const uint4 hv, const uint4 tv,
    const float4 cq, const float4 sq, const float4 ka, const float4 kb,
    const float4 hp) {
  union U2 { unsigned int u; __half2 h; };
  U2 u0, u1, u2, u3;
  u0.u = hv.x; u1.u = hv.y; u2.u = hv.z; u3.u = hv.w;
  const float2 fa01 = __half22float2(u0.h);
  const float2 fa23 = __half22float2(u1.h);
  const float2 fb01 = __half22float2(u2.h);
  const float2 fb23 = __half22float2(u3.h);
  const float a0 = fa01.x, a1 = fa01.y, a2 = fa23.x, a3 = fa23.y;
  const float b0 = fb01.x, b1 = fb01.y, b2 = fb23.x, b3 = fb23.y;

  float hsq = a0 * a0;
  hsq = fmaf(a1, a1, hsq); hsq = fmaf(a2, a2, hsq); hsq = fmaf(a3, a3, hsq);
  hsq = fmaf(b0, b0, hsq); hsq = fmaf(b1, b1, hsq);
  hsq = fmaf(b2, b2, hsq); hsq = fmaf(b3, b3, hsq);
  hsq += __shfl_xor(hsq, 1);
  hsq += __shfl_xor(hsq, 2);
  const float x0 = sqrtf(1.f + hsq);          // head time component

  float rA0 = cq.x * a0 - sq.x * b0;
  float rA1 = cq.y * a1 - sq.y * b1;
  float rA2 = cq.z * a2 - sq.z * b2;
  float rA3 = cq.w * a3 - sq.w * b3;
  const float rB0 = fmaf(sq.x, a0, cq.x * b0);
  const float rB1 = fmaf(sq.y, a1, cq.y * b1);
  const float rB2 = fmaf(sq.z, a2, cq.z * b2);
  const float rB3 = fmaf(sq.w, a3, cq.w * b3);

  if (q == 0) rA0 = fmaf(x0, hp.y, rA0 * hp.x);   // boost: spatial dim 0 only
  const float cvn = hp.z;

  const float sA0 = fmaf(cvn, rA0, ka.x);
  const float sA1 = fmaf(cvn, rA1, ka.y);
  const float sA2 = fmaf(cvn, rA2, ka.z);
  const float sA3 = fmaf(cvn, rA3, ka.w);
  const float sB0 = fmaf(cvn, rB0, kb.x);
  const float sB1 = fmaf(cvn, rB1, kb.y);
  const float sB2 = fmaf(cvn, rB2, kb.z);
  const float sB3 = fmaf(cvn, rB3, kb.w);

  float n2 = sA0 * sA0;
  n2 = fmaf(sA1, sA1, n2); n2 = fmaf(sA2, sA2, n2); n2 = fmaf(sA3, sA3, n2);
  n2 = fmaf(sB0, sB0, n2); n2 = fmaf(sB1, sB1, n2);
  n2 = fmaf(sB2, sB2, n2); n2 = fmaf(sB3, sB3, n2);
  n2 += __shfl_xor(n2, 1);
  n2 += __shfl_xor(n2, 2);
  const float ht0 = sqrtf(1.f + n2);

  U2 w0, w1, w2, w3;
  w0.u = tv.x; w1.u = tv.y; w2.u = tv.z; w3.u = tv.w;
  const float2 ta01 = __half22float2(w0.h);
  const float2 ta23 = __half22float2(w1.h);
  const float2 tb01 = __half22float2(w2.h);
  const float2 tb23 = __half22float2(w3.h);

  float dot = sA0 * ta01.x;
  dot = fmaf(sA1, ta01.y, dot); dot = fmaf(sA2, ta23.x, dot);
  dot = fmaf(sA3, ta23.y, dot);
  dot = fmaf(sB0, tb01.x, dot); dot = fmaf(sB1, tb01.y, dot);
  dot = fmaf(sB2, tb23.x, dot); dot = fmaf(sB3, tb23.y, dot);

  float tsq = ta01.x * ta01.x;
  tsq = fmaf(ta01.y, ta01.y, tsq); tsq = fmaf(ta23.x, ta23.x, tsq);
  tsq = fmaf(ta23.y, ta23.y, tsq);
  tsq = fmaf(tb01.x, tb01.x, tsq); tsq = fmaf(tb01.y, tb01.y, tsq);
  tsq = fmaf(tb23.x, tb23.x, tsq);

  dot += __shfl_xor(dot, 1);
  dot += __shfl_xor(dot, 2);
  tsq = fmaf(tb23.y, tb23.y, tsq);
  tsq += __shfl_xor(tsq, 1);
  tsq += __shfl_xor(tsq, 2);
  const float t0 = sqrtf(1.f + tsq);          // tail time component

  const float neg_inner = fmaf(ht0, t0, -dot); // -lorentz_inner
  const float ic = fmaxf(neg_inner, 1.0f + 1e-6f);
  const float dist = acoshf(ic);
  return -dist * dist;
}

// ---------------------------------------------------------------------------
// Kernel 1: main scoring. 4-lane group owns TWO consecutive elements.
// Rationale (R2 ord-99 evidence: duration invariant to cache state -> the
// gather kernel is REQUEST/issue-bound, not BW-bound):
//  - 2 elems/group halves wave count (65.6K -> 32.8K) and per-wave overhead;
//  - 4 uint4 row-gathers in flight per lane (deeper vmcnt queue);
//  - index loads vectorized (3x int2 for 2 elements);
//  - both stores merged into ONE instruction (lane q==0 -> e0, q==1 -> e1);
//  - tab rows now 64B-aligned (stride 320 B): every per-group tab access is
//    exactly one line request (was 1-2).
// ---------------------------------------------------------------------------
__global__ __launch_bounds__(256) void lorentz_coop2_kernel(
    const int* __restrict__ heads, const int* __restrict__ rels,
    const int* __restrict__ tails, const unsigned int* __restrict__ h16,
    const float* __restrict__ bias, const float* __restrict__ tab,
    float* __restrict__ out, int n) {
  const int q  = threadIdx.x & 3;                      // dim-chunk in group
  const int g  = (blockIdx.x * 256 + threadIdx.x) >> 2; // group id
  const int e0 = g * 2, e1 = e0 + 1;
  const int i0 = (e0 < n) ? e0 : (n - 1);              // clamp: lanes active
  const int i1 = (e1 < n) ? e1 : (n - 1);

  // ---- Vectorized index loads (e0 even -> 8B aligned) ----
  const int2 hh = *reinterpret_cast<const int2*>(heads + i0);
  const int2 rr = *reinterpret_cast<const int2*>(rels  + i0);
  const int2 tt = *reinterpret_cast<const int2*>(tails + i0);
  const int hd0 = hh.x, hd1 = (e1 < n) ? hh.y : hh.x;
  const int rl0 = rr.x, rl1 = (e1 < n) ? rr.y : rr.x;
  const int tl0 = tt.x, tl1 = (e1 < n) ? tt.y : tt.x;

  // ---- Issue ALL four row gathers back-to-back (4 outstanding) ----
  const uint4 hv0 = *reinterpret_cast<const uint4*>(h16 + (size_t)hd0 * 16 + 4 * q);
  const uint4 tv0 = *reinterpret_cast<const uint4*>(h16 + (size_t)tl0 * 16 + 4 * q);
  const uint4 hv1 = *reinterpret_cast<const uint4*>(h16 + (size_t)hd1 * 16 + 4 * q);
  const uint4 tv1 = *reinterpret_cast<const uint4*>(h16 + (size_t)tl1 * 16 + 4 * q);

  // ---- Relation tables (64B-aligned blocks; 1 line-request per group) ----
  const float4* __restrict__ T0 =
      reinterpret_cast<const float4*>(tab + (size_t)rl0 * TAB_STRIDE);
  const float4* __restrict__ T1 =
      reinterpret_cast<const float4*>(tab + (size_t)rl1 * TAB_STRIDE);
  const float4 cq0 = T0[q],      cq1 = T1[q];
  const float4 sq0 = T0[4 + q],  sq1 = T1[4 + q];
  const float4 ka0 = T0[8 + q],  ka1 = T1[8 + q];
  const float4 kb0 = T0[12 + q], kb1 = T1[12 + q];
  const float4 hp0 = T0[16],     hp1 = T1[16];

  const float bsum0 = bias[hd0] + bias[tl0];
  const float bsum1 = bias[hd1] + bias[tl1];

  const float s0 = score_one(q, hv0, tv0, cq0, sq0, ka0, kb0, hp0);
  const float s1 = score_one(q, hv1, tv1, cq1, sq1, ka1, kb1, hp1);

  // ---- Single merged store: lane q==0 -> e0, lane q==1 -> e1 ----
  const float res = (q == 0) ? (bsum0 + s0) : (bsum1 + s1);
  const int   eo  = (q == 0) ? e0 : e1;
  if (q < 2 && eo < n) out[eo] = res;
}

// ---------------------------------------------------------------------------
// Fallback (ws too small): fully inline fp32 scalar path (proven).
// ---------------------------------------------------------------------------
__global__ __launch_bounds__(256) void lorentz_fallback_kernel(
    const int* __restrict__ heads, const int* __restrict__ rels,
    const int* __restrict__ tails, const float* __restrict__ emb,
    const float* __restrict__ boost_w, const float* __restrict__ rot_w,
    const float* __restrict__ trans_w, const float* __restrict__ bias,
    float* __restrict__ out, int n) {
  int i = blockIdx.x * blockDim.x + threadIdx.x;
  if (i >= n) return;
  int hd = heads[i], rl = rels[i], tl = tails[i];
  const float* hrow = emb + (size_t)hd * EMB_DIM;
  const float* trow = emb + (size_t)tl * EMB_DIM;
  const float* ro = rot_w   + (size_t)rl * D_;
  const float* tr = trans_w + (size_t)rl * D_;
  float c[HALF_], s[HALF_], kt[D_];
  #pragma unroll
  for (int j = 0; j < HALF_; ++j) { float th = ro[j]; c[j] = cosf(th); s[j] = sinf(th); }
  float s2 = 0.f;
  #pragma unroll
  for (int j = 0; j < D_; ++j) { float v = tr[j]; s2 = fmaf(v, v, s2); }
  float vn = sqrtf(fmaxf(0.01f * s2, 1e-6f));
  float cvn = coshf(vn);
  float k = sinhf(vn) / vn * 0.1f;
  #pragma unroll
  for (int j = 0; j < D_; ++j) kt[j] = k * tr[j];
  float rap = fminf(fmaxf(boost_w[(size_t)rl * D_], -2.f), 2.f);
  float c0 = coshf(rap), s0 = sinhf(rap);
  float x0 = hrow[0];
  float r[D_];
  #pragma unroll
  for (int j = 0; j < HALF_; ++j) {
    float a = hrow[1 + j], b = hrow[1 + HALF_ + j];
    r[j] = c[j] * a - s[j] * b;
    r[HALF_ + j] = s[j] * a + c[j] * b;
  }
  r[0] = fmaf(x0, s0, r[0] * c0);
  float t0 = trow[0], n2 = 0.f, dot = 0.f;
  #pragma unroll
  for (int j = 0; j < D_; ++j) {
    float rsv = fmaf(cvn, r[j], kt[j]);
    n2  = fmaf(rsv, rsv, n2);
    dot = fmaf(rsv, trow[1 + j], dot);
  }
  float ht0 = sqrtf(1.f + n2);
  float neg_inner = fmaf(ht0, t0, -dot);
  float ic = fmaxf(neg_inner, 1.0f + 1e-6f);
  float dist = acoshf(ic);
  out[i] = bias[hd] + bias[tl] - dist * dist;
}

extern "C" void kernel_launch(void* const* d_in, const int* in_sizes, int n_in,
                              void* d_out, int out_size, void* d_ws, size_t ws_size,
                              hipStream_t stream) {
  const int*   heads  = (const int*)d_in[0];
  const int*   rels   = (const int*)d_in[1];
  const int*   tails  = (const int*)d_in[2];
  const float* emb    = (const float*)d_in[3];
  const float* boostw = (const float*)d_in[4];
  const float* rotw   = (const float*)d_in[5];
  const float* transw = (const float*)d_in[6];
  const float* bias   = (const float*)d_in[7];
  float* out = (float*)d_out;
  int n = in_sizes[0];  // B = 1048576

  const size_t tab_bytes = (size_t)NR_ * TAB_STRIDE * sizeof(float);
  dim3 block(256);

  if (ws_size >= H16_BYTES + tab_bytes) {
    unsigned int* h16 = (unsigned int*)d_ws;
    float* tab = (float*)((char*)d_ws + H16_BYTES);   // 64B-aligned
    prep_kernel<<<dim3(REPACK_BLOCKS + TAB_BLOCKS), block, 0, stream>>>(
        emb, boostw, rotw, transw, h16, tab);
    dim3 grid_main((n + 127) / 128);   // 2 elements per 4-lane group
    lorentz_coop2_kernel<<<grid_main, block, 0, stream>>>(
        heads, rels, tails, h16, bias, tab, out, n);
  } else {
    dim3 grid((n + 255) / 256);
    lorentz_fallback_kernel<<<grid, block, 0, stream>>>(
        heads, rels, tails, emb, boostw, rotw, transw, bias, out, n);
  }
}

// Round 7
// 271.991 us; speedup vs baseline: 1.0213x; 1.0213x over previous
//
#include <hip/hip_runtime.h>
#include <hip/hip_fp16.h>
#include <math.h>

// Problem constants: NE=1e6, NR=1000, D=32, B=2^20, CURV=1
#define NR_ 1000
#define NE_ 1000000
#define D_ 32
#define HALF_ 16
#define EMB_DIM 33            // fp32 entity row: [x0, spatial(32)]
#define H16_BYTES ((size_t)NE_ * 64)   // fp16 entity table: 64 B rows
#define T16_HALVES 64                  // fp16 tab row: 64 halves = 128 B, 2 lines
#define T16_BYTES ((size_t)NR_ * T16_HALVES * 2)     // 128 KB
#define HP_BYTES ((size_t)NR_ * 16)                  // 16 KB float4 table
#define ROWS_PER_BLOCK 64
#define FLOATS_PER_BLOCK (ROWS_PER_BLOCK * EMB_DIM)  // 2112
#define REPACK_BLOCKS (NE_ / ROWS_PER_BLOCK)         // 15625
#define TAB_BLOCKS 16          // 16*256 = 4096 >= NR*4 lanes

// ---------------------------------------------------------------------------
// Kernel 0 (fused prep), LDS-staged streaming repack (R5-proven) + NEW
// 2-line fp16 relation table.
// Entity rows: fp16 INTERLEAVED, chunk q = {sp[4q..4q+3], sp[16+4q..+3]}.
// Relation row r (128 B stride, 64B-aligned, ushort* tab16):
//   line 0 (halves [0,32)),  chunk q = halves [8q..8q+8):
//       {cos(rot)[4q..4q+3], sin(rot)[4q..4q+3]}
//   line 1 (halves [32,64)), chunk q:
//       {kt[4q..4q+3], kt[16+4q..16+4q+3]}   (kt = sinh(vn)/vn*0.1*trans)
// hp_tab[r] = float4{cosh(rap0), sinh(rap0), cosh(vn), 0} — 16 KB dense,
// L1-resident in the main kernel (vs one 64 B line-request per element).
// Per-element divergent requests in main drop 9.4 -> ~6.4.
// ---------------------------------------------------------------------------
__global__ __launch_bounds__(256) void prep_kernel(
    const float* __restrict__ emb, const float* __restrict__ boost_w,
    const float* __restrict__ rot_w, const float* __restrict__ trans_w,
    unsigned int* __restrict__ h16, unsigned short* __restrict__ tab16,
    float4* __restrict__ hp_tab) {
  const int b = blockIdx.x;
  if (b < REPACK_BLOCKS) {
    __shared__ float s[FLOATS_PER_BLOCK];
    const int tid = threadIdx.x;
    const float* __restrict__ src = emb + (size_t)b * FLOATS_PER_BLOCK;
    #pragma unroll
    for (int k = 0; k < 8; ++k) s[tid + k * 256] = src[tid + k * 256];
    if (tid < FLOATS_PER_BLOCK - 2048) s[2048 + tid] = src[2048 + tid];
    __syncthreads();

    const int r = tid >> 2, q = tid & 3;                 // row 0..63, chunk
    const float* p = s + r * EMB_DIM + 1 + 4 * q;        // a-dims 4q..4q+3
    float a0 = p[0], a1 = p[1], a2 = p[2], a3 = p[3];
    float b0 = p[HALF_], b1 = p[HALF_ + 1], b2 = p[HALF_ + 2], b3 = p[HALF_ + 3];
    union { __half2 h; unsigned int u; } c0, c1, c2, c3;
    c0.h = __half2(__float2half_rn(a0), __float2half_rn(a1));
    c1.h = __half2(__float2half_rn(a2), __float2half_rn(a3));
    c2.h = __half2(__float2half_rn(b0), __float2half_rn(b1));
    c3.h = __half2(__float2half_rn(b2), __float2half_rn(b3));
    uint4 v = make_uint4(c0.u, c1.u, c2.u, c3.u);
    const size_t row = (size_t)b * ROWS_PER_BLOCK + r;
    *reinterpret_cast<uint4*>(h16 + row * 16 + 4 * q) = v;   // 16B aligned
    return;
  }
  // ---- tab build: 4 lanes per relation ----
  const int t = (b - REPACK_BLOCKS) * 256 + threadIdx.x;
  const int r = t >> 2, q = t & 3;
  if (r >= NR_) return;
  const float* ro = rot_w   + (size_t)r * D_ + 4 * q;       // rot dims 4q..
  const float* ta = trans_w + (size_t)r * D_ + 4 * q;       // trans a-dims
  const float* tb = ta + HALF_;                             // trans b-dims

  float ta0 = ta[0], ta1 = ta[1], ta2 = ta[2], ta3 = ta[3];
  float tb0 = tb[0], tb1 = tb[1], tb2 = tb[2], tb3 = tb[3];
  float s2 = ta0 * ta0;
  s2 = fmaf(ta1, ta1, s2); s2 = fmaf(ta2, ta2, s2); s2 = fmaf(ta3, ta3, s2);
  s2 = fmaf(tb0, tb0, s2); s2 = fmaf(tb1, tb1, s2);
  s2 = fmaf(tb2, tb2, s2); s2 = fmaf(tb3, tb3, s2);
  s2 += __shfl_xor(s2, 1);
  s2 += __shfl_xor(s2, 2);

  float vn = sqrtf(fmaxf(0.01f * s2, 1e-6f));
  float k  = sinhf(vn) / vn * 0.1f;

  const float cc0 = cosf(ro[0]), cc1 = cosf(ro[1]),
              cc2 = cosf(ro[2]), cc3 = cosf(ro[3]);
  const float ss0 = sinf(ro[0]), ss1 = sinf(ro[1]),
              ss2 = sinf(ro[2]), ss3 = sinf(ro[3]);

  union { __half2 h; unsigned int u; } p0, p1, p2, p3;
  // line 0 chunk q: {c0..c3, s0..s3}
  p0.h = __half2(__float2half_rn(cc0), __float2half_rn(cc1));
  p1.h = __half2(__float2half_rn(cc2), __float2half_rn(cc3));
  p2.h = __half2(__float2half_rn(ss0), __float2half_rn(ss1));
  p3.h = __half2(__float2half_rn(ss2), __float2half_rn(ss3));
  *reinterpret_cast<uint4*>(tab16 + (size_t)r * T16_HALVES + 8 * q) =
      make_uint4(p0.u, p1.u, p2.u, p3.u);
  // line 1 chunk q: {kta0..3, ktb0..3}
  p0.h = __half2(__float2half_rn(k * ta0), __float2half_rn(k * ta1));
  p1.h = __half2(__float2half_rn(k * ta2), __float2half_rn(k * ta3));
  p2.h = __half2(__float2half_rn(k * tb0), __float2half_rn(k * tb1));
  p3.h = __half2(__float2half_rn(k * tb2), __float2half_rn(k * tb3));
  *reinterpret_cast<uint4*>(tab16 + (size_t)r * T16_HALVES + 32 + 8 * q) =
      make_uint4(p0.u, p1.u, p2.u, p3.u);

  if (q == 0) {
    float rap = fminf(fmaxf(boost_w[(size_t)r * D_], -2.f), 2.f);
    hp_tab[r] = make_float4(coshf(rap), sinhf(rap), coshf(vn), 0.f);
  }
}

// ---------------------------------------------------------------------------
// Kernel 1: main scoring, 4-lane-cooperative, LDS-free, fp16 everywhere.
// Per-element divergent line-requests: head 1 + tail 1 + rot 1 + kt 1 +
// bias 2 + hp (16 KB table, L1-resident ~ free) ~= 6.4  (was ~9.4).
// R2 evidence says this kernel's duration ~ requests/elem, so -30% expected.
// Arithmetic identical to the R5-proven path; cos/sin/kt now fp16
// (abs err ~1e-5 on dims ~0.04 — negligible vs existing fp16-dims error).
// ---------------------------------------------------------------------------
__global__ __launch_bounds__(256) void lorentz_coop_kernel(
    const int* __restrict__ heads, const int* __restrict__ rels,
    const int* __restrict__ tails, const unsigned int* __restrict__ h16,
    const unsigned short* __restrict__ tab16, const float4* __restrict__ hp_tab,
    const float* __restrict__ bias, float* __restrict__ out, int n) {
  const int q = threadIdx.x & 3;                      // dim-chunk within group
  const int e = (blockIdx.x * 256 + threadIdx.x) >> 2; // element id
  const int i = (e < n) ? e : (n - 1);                // clamp: lanes stay active

  const int hd = heads[i];
  const int rl = rels[i];
  const int tl = tails[i];

  // ---- Issue ALL divergent loads back-to-back (deep vmcnt queue) ----
  const uint4 hv = *reinterpret_cast<const uint4*>(h16 + (size_t)hd * 16 + 4 * q);
  const uint4 tv = *reinterpret_cast<const uint4*>(h16 + (size_t)tl * 16 + 4 * q);
  const uint4 rv = *reinterpret_cast<const uint4*>(
      tab16 + (size_t)rl * T16_HALVES + 8 * q);          // {c0..3, s0..3}
  const uint4 kv = *reinterpret_cast<const uint4*>(
      tab16 + (size_t)rl * T16_HALVES + 32 + 8 * q);     // {kta0..3, ktb0..3}
  const float4 hp = hp_tab[rl];   // L1-resident (16 KB), broadcast in group
  const float bsum = bias[hd] + bias[tl];

  union U2 { unsigned int u; __half2 h; };
  // ---- Unpack rotation constants ----
  U2 rc0, rc1, rs0, rs1;
  rc0.u = rv.x; rc1.u = rv.y; rs0.u = rv.z; rs1.u = rv.w;
  const float2 c01 = __half22float2(rc0.h), c23 = __half22float2(rc1.h);
  const float2 s01 = __half22float2(rs0.h), s23 = __half22float2(rs1.h);
  // ---- Unpack kt ----
  U2 k0, k1, k2, k3;
  k0.u = kv.x; k1.u = kv.y; k2.u = kv.z; k3.u = kv.w;
  const float2 ka01 = __half22float2(k0.h), ka23 = __half22float2(k1.h);
  const float2 kb01 = __half22float2(k2.h), kb23 = __half22float2(k3.h);

  // ---- Head unpack: 8 fp16 dims for this lane ----
  U2 u0, u1, u2, u3;
  u0.u = hv.x; u1.u = hv.y; u2.u = hv.z; u3.u = hv.w;
  const float2 fa01 = __half22float2(u0.h);
  const float2 fa23 = __half22float2(u1.h);
  const float2 fb01 = __half22float2(u2.h);
  const float2 fb23 = __half22float2(u3.h);
  const float a0 = fa01.x, a1 = fa01.y, a2 = fa23.x, a3 = fa23.y;
  const float b0 = fb01.x, b1 = fb01.y, b2 = fb23.x, b3 = fb23.y;

  // ---- hsq = sum over all 32 spatial dims (4-lane reduce) ----
  float hsq = a0 * a0;
  hsq = fmaf(a1, a1, hsq); hsq = fmaf(a2, a2, hsq); hsq = fmaf(a3, a3, hsq);
  hsq = fmaf(b0, b0, hsq); hsq = fmaf(b1, b1, hsq);
  hsq = fmaf(b2, b2, hsq); hsq = fmaf(b3, b3, hsq);
  hsq += __shfl_xor(hsq, 1);
  hsq += __shfl_xor(hsq, 2);
  const float x0 = sqrtf(1.f + hsq);          // head time component

  // ---- Rotation (pairs (j, 16+j) are in-lane by construction) ----
  float rA0 = c01.x * a0 - s01.x * b0;
  float rA1 = c01.y * a1 - s01.y * b1;
  float rA2 = c23.x * a2 - s23.x * b2;
  float rA3 = c23.y * a3 - s23.y * b3;
  const float rB0 = fmaf(s01.x, a0, c01.x * b0);
  const float rB1 = fmaf(s01.y, a1, c01.y * b1);
  const float rB2 = fmaf(s23.x, a2, c23.x * b2);
  const float rB3 = fmaf(s23.y, a3, c23.y * b3);

  // ---- Boost touches spatial dim 0 only (lane q==0) ----
  if (q == 0) rA0 = fmaf(x0, hp.y, rA0 * hp.x);
  const float cvn = hp.z;

  // ---- Translation: rs = cvn*r + kt ----
  const float sA0 = fmaf(cvn, rA0, ka01.x);
  const float sA1 = fmaf(cvn, rA1, ka01.y);
  const float sA2 = fmaf(cvn, rA2, ka23.x);
  const float sA3 = fmaf(cvn, rA3, ka23.y);
  const float sB0 = fmaf(cvn, rB0, kb01.x);
  const float sB1 = fmaf(cvn, rB1, kb01.y);
  const float sB2 = fmaf(cvn, rB2, kb23.x);
  const float sB3 = fmaf(cvn, rB3, kb23.y);

  float n2 = sA0 * sA0;
  n2 = fmaf(sA1, sA1, n2); n2 = fmaf(sA2, sA2, n2); n2 = fmaf(sA3, sA3, n2);
  n2 = fmaf(sB0, sB0, n2); n2 = fmaf(sB1, sB1, n2);
  n2 = fmaf(sB2, sB2, n2); n2 = fmaf(sB3, sB3, n2);
  n2 += __shfl_xor(n2, 1);
  n2 += __shfl_xor(n2, 2);
  const float ht0 = sqrtf(1.f + n2);

  // ---- Tail unpack + dot / tsq (4-lane reduce) ----
  U2 w0, w1, w2, w3;
  w0.u = tv.x; w1.u = tv.y; w2.u = tv.z; w3.u = tv.w;
  const float2 ta01 = __half22float2(w0.h);
  const float2 ta23 = __half22float2(w1.h);
  const float2 tb01 = __half22float2(w2.h);
  const float2 tb23 = __half22float2(w3.h);

  float dot = sA0 * ta01.x;
  dot = fmaf(sA1, ta01.y, dot); dot = fmaf(sA2, ta23.x, dot);
  dot = fmaf(sA3, ta23.y, dot);
  dot = fmaf(sB0, tb01.x, dot); dot = fmaf(sB1, tb01.y, dot);
  dot = fmaf(sB2, tb23.x, dot); dot = fmaf(sB3, tb23.y, dot);

  float tsq = ta01.x * ta01.x;
  tsq = fmaf(ta01.y, ta01.y, tsq); tsq = fmaf(ta23.x, ta23.x, tsq);
  tsq = fmaf(ta23.y, ta23.y, tsq);
  tsq = fmaf(tb01.x, tb01.x, tsq); tsq = fmaf(tb01.y, tb01.y, tsq);
  tsq = fmaf(tb23.x, tb23.x, tsq); tsq = fmaf(tb23.y, tb23.y, tsq);

  dot += __shfl_xor(dot, 1);
  dot += __shfl_xor(dot, 2);
  tsq += __shfl_xor(tsq, 1);
  tsq += __shfl_xor(tsq, 2);
  const float t0 = sqrtf(1.f + tsq);          // tail time component

  const float neg_inner = fmaf(ht0, t0, -dot); // -lorentz_inner
  const float ic = fmaxf(neg_inner, 1.0f + 1e-6f);
  const float dist = acoshf(ic);
  if (q == 0 && e < n) out[e] = bsum - dist * dist;
}

// ---------------------------------------------------------------------------
// Fallback (ws too small): fully inline fp32 scalar path (proven).
// ---------------------------------------------------------------------------
__global__ __launch_bounds__(256) void lorentz_fallback_kernel(
    const int* __restrict__ heads, const int* __restrict__ rels,
    const int* __restrict__ tails, const float* __restrict__ emb,
    const float* __restrict__ boost_w, const float* __restrict__ rot_w,
    const float* __restrict__ trans_w, const float* __restrict__ bias,
    float* __restrict__ out, int n) {
  int i = blockIdx.x * blockDim.x + threadIdx.x;
  if (i >= n) return;
  int hd = heads[i], rl = rels[i], tl = tails[i];
  const float* hrow = emb + (size_t)hd * EMB_DIM;
  const float* trow = emb + (size_t)tl * EMB_DIM;
  const float* ro = rot_w   + (size_t)rl * D_;
  const float* tr = trans_w + (size_t)rl * D_;
  float c[HALF_], s[HALF_], kt[D_];
  #pragma unroll
  for (int j = 0; j < HALF_; ++j) { float th = ro[j]; c[j] = cosf(th); s[j] = sinf(th); }
  float s2 = 0.f;
  #pragma unroll
  for (int j = 0; j < D_; ++j) { float v = tr[j]; s2 = fmaf(v, v, s2); }
  float vn = sqrtf(fmaxf(0.01f * s2, 1e-6f));
  float cvn = coshf(vn);
  float k = sinhf(vn) / vn * 0.1f;
  #pragma unroll
  for (int j = 0; j < D_; ++j) kt[j] = k * tr[j];
  float rap = fminf(fmaxf(boost_w[(size_t)rl * D_], -2.f), 2.f);
  float c0 = coshf(rap), s0 = sinhf(rap);
  float x0 = hrow[0];
  float r[D_];
  #pragma unroll
  for (int j = 0; j < HALF_; ++j) {
    float a = hrow[1 + j], b = hrow[1 + HALF_ + j];
    r[j] = c[j] * a - s[j] * b;
    r[HALF_ + j] = s[j] * a + c[j] * b;
  }
  r[0] = fmaf(x0, s0, r[0] * c0);
  float t0 = trow[0], n2 = 0.f, dot = 0.f;
  #pragma unroll
  for (int j = 0; j < D_; ++j) {
    float rsv = fmaf(cvn, r[j], kt[j]);
    n2  = fmaf(rsv, rsv, n2);
    dot = fmaf(rsv, trow[1 + j], dot);
  }
  float ht0 = sqrtf(1.f + n2);
  float neg_inner = fmaf(ht0, t0, -dot);
  float ic = fmaxf(neg_inner, 1.0f + 1e-6f);
  float dist = acoshf(ic);
  out[i] = bias[hd] + bias[tl] - dist * dist;
}

extern "C" void kernel_launch(void* const* d_in, const int* in_sizes, int n_in,
                              void* d_out, int out_size, void* d_ws, size_t ws_size,
                              hipStream_t stream) {
  const int*   heads  = (const int*)d_in[0];
  const int*   rels   = (const int*)d_in[1];
  const int*   tails  = (const int*)d_in[2];
  const float* emb    = (const float*)d_in[3];
  const float* boostw = (const float*)d_in[4];
  const float* rotw   = (const float*)d_in[5];
  const float* transw = (const float*)d_in[6];
  const float* bias   = (const float*)d_in[7];
  float* out = (float*)d_out;
  int n = in_sizes[0];  // B = 1048576

  dim3 block(256);

  if (ws_size >= H16_BYTES + T16_BYTES + HP_BYTES) {
    unsigned int* h16 = (unsigned int*)d_ws;
    unsigned short* tab16 = (unsigned short*)((char*)d_ws + H16_BYTES);
    float4* hp_tab = (float4*)((char*)d_ws + H16_BYTES + T16_BYTES);
    prep_kernel<<<dim3(REPACK_BLOCKS + TAB_BLOCKS), block, 0, stream>>>(
        emb, boostw, rotw, transw, h16, tab16, hp_tab);
    dim3 grid_main((n + 63) / 64);   // 4 lanes per element, 64 elems/block
    lorentz_coop_kernel<<<grid_main, block, 0, stream>>>(
        heads, rels, tails, h16, tab16, hp_tab, bias, out, n);
  } else {
    dim3 grid((n + 255) / 256);
    lorentz_fallback_kernel<<<grid, block, 0, stream>>>(
        heads, rels, tails, emb, boostw, rotw, transw, bias, out, n);
  }
}